// Round 7
// baseline (1992.772 us; speedup 1.0000x reference)
//
#include <hip/hip_runtime.h>
#include <hip/hip_bf16.h>

typedef __bf16 bf16_t;
typedef bf16_t bf16x8 __attribute__((ext_vector_type(8)));
typedef float f32x4 __attribute__((ext_vector_type(4)));
typedef unsigned short ushort_t;

#define LD 104   // padded LDS row stride (bf16 elems) for GEMM staging tiles

__device__ __forceinline__ float bf2f(unsigned short u) {
    return __uint_as_float(((unsigned)u) << 16);
}
__device__ __forceinline__ unsigned short f2bfu(float x) {
    union { bf16_t b; unsigned short u; } c; c.b = (bf16_t)x; return c.u;
}
__device__ __forceinline__ unsigned pk2(float x, float y) {
    return (unsigned)f2bfu(x) | ((unsigned)f2bfu(y) << 16);
}

// load 6 consecutive bf16 (as 3 dwords) -> 6 floats
#define LD6(PTR, OUT) { \
    unsigned u0 = *(const unsigned*)(PTR); \
    unsigned u1 = *(const unsigned*)((PTR) + 2); \
    unsigned u2 = *(const unsigned*)((PTR) + 4); \
    OUT[0] = bf2f(u0 & 0xffff); OUT[1] = bf2f(u0 >> 16); \
    OUT[2] = bf2f(u1 & 0xffff); OUT[3] = bf2f(u1 >> 16); \
    OUT[4] = bf2f(u2 & 0xffff); OUT[5] = bf2f(u2 >> 16); }

// ---------------- weight convert: 5 x [96][96] f32 -> bf16 ----------------
__global__ void conv_w_kernel(const float* __restrict__ A, const float* __restrict__ B,
                              const float* __restrict__ C, const float* __restrict__ Dw,
                              const float* __restrict__ Ew, bf16_t* __restrict__ wb) {
    int i = blockIdx.x * 256 + threadIdx.x;
    if (i >= 5 * 9216) return;
    int m = i / 9216, j = i % 9216;
    const float* p = (m == 0) ? A : (m == 1) ? B : (m == 2) ? C : (m == 3) ? Dw : Ew;
    wb[i] = (bf16_t)p[j];
}

// ---------------- pack C_w into per-lane MFMA B-fragment order ----------------
// col remap: tile col c (=lane&15) of tile tn -> physical col c*6 + tn
__global__ void pack_cw_kernel(const float* __restrict__ Cw, bf16_t* __restrict__ wpack) {
    int idx = blockIdx.x * 256 + threadIdx.x;
    if (idx >= 18 * 64) return;
    int frag = idx >> 6, l = idx & 63;
    int tn = frag / 3, kk = frag % 3;
    int row = (l & 15) * 6 + tn;
    int c0 = kk * 32 + (l >> 4) * 8;
    bf16_t* o = wpack + (size_t)idx * 8;
#pragma unroll
    for (int j = 0; j < 8; ++j) o[j] = (bf16_t)Cw[row * 96 + c0 + j];
}

// ---------------- node GEMM ----------------
// mat 0 -> Ah (f32, nodeF_A[n][96]); mat 1,2,3 -> Bh,Dh,El(+Cb) bf16 into gpack[n][288]
__global__ __launch_bounds__(256) void node_gemm_kernel(
    const float* __restrict__ h, const bf16_t* __restrict__ wb,
    const float* __restrict__ Ab, const float* __restrict__ Bb,
    const float* __restrict__ Db, const float* __restrict__ Eb,
    const float* __restrict__ Cb,
    float* __restrict__ nodeF_A, ushort_t* __restrict__ gpack, int N)
{
    __shared__ __align__(16) bf16_t sx[64 * LD];
    __shared__ __align__(16) bf16_t sw[96 * LD];
    const int mat = blockIdx.y;
    const int widx = (mat < 2) ? mat : mat + 1;
    const float* bias = (mat == 0) ? Ab : (mat == 1) ? Bb : (mat == 2) ? Db : Eb;
    const int n0 = blockIdx.x * 64;
    const int t = threadIdx.x;

    for (int i = t; i < 64 * 96; i += 256) {
        int r = i / 96, c = i % 96;
        int n = n0 + r;
        float v = (n < N) ? h[n * 96 + c] : 0.f;
        sx[r * LD + c] = (bf16_t)v;
    }
    {
        const unsigned* W4 = (const unsigned*)(wb + widx * 9216);
        for (int i = t; i < 96 * 48; i += 256) {
            int r = i / 48, c = (i % 48) * 2;
            *(unsigned*)&sw[r * LD + c] = W4[i];
        }
    }
    __syncthreads();

    const int w = t >> 6, l = t & 63;
    const int lr = l & 15, lkb = (l >> 4) * 8;
    f32x4 acc[6];
#pragma unroll
    for (int i = 0; i < 6; ++i) acc[i] = (f32x4){0.f, 0.f, 0.f, 0.f};
    const bf16_t* aP = &sx[(w * 16 + lr) * LD + lkb];
#pragma unroll
    for (int kk = 0; kk < 3; ++kk) {
        bf16x8 a = *(const bf16x8*)(aP + kk * 32);
#pragma unroll
        for (int tn = 0; tn < 6; ++tn) {
            bf16x8 b = *(const bf16x8*)(&sw[(tn * 16 + lr) * LD + kk * 32 + lkb]);
            acc[tn] = __builtin_amdgcn_mfma_f32_16x16x32_bf16(a, b, acc[tn], 0, 0, 0);
        }
    }
    const int rowb = (l >> 4) * 4;
#pragma unroll
    for (int tn = 0; tn < 6; ++tn) {
        const int col = tn * 16 + lr;
        float bv = bias[col];
        if (mat == 3) bv += Cb[col];
#pragma unroll
        for (int i = 0; i < 4; ++i) {
            int n = n0 + w * 16 + rowb + i;
            if (n < N) {
                float v = acc[tn][i] + bv;
                if (mat == 0) nodeF_A[(size_t)n * 96 + col] = v;
                else gpack[(size_t)n * 288 + (mat - 1) * 96 + col] = f2bfu(v);
            }
        }
    }
}

// ---------------- Ce GEMM: en_s[inv[row]][96] = bf16(e[row] @ Cw^T) ----------------
// sequential e read; scatter WRITE into dst-sorted slot (writes don't stall).
__global__ __launch_bounds__(256) void ce_gemm_kernel(
    const float* __restrict__ eP, const bf16_t* __restrict__ wpack,
    const int* __restrict__ inv, ushort_t* __restrict__ en_s, int E)
{
    __shared__ __align__(16) bf16_t sx[64 * LD];
    const int n0 = blockIdx.x * 64;
    const int t = threadIdx.x;
    for (int i = t; i < 64 * 24; i += 256) {
        int r = i / 24, c4 = i % 24;
        int n = n0 + r;
        float4 v = (n < E) ? ((const float4*)eP)[(size_t)n * 24 + c4]
                           : make_float4(0.f, 0.f, 0.f, 0.f);
        bf16_t* p = &sx[r * LD + c4 * 4];
        p[0] = (bf16_t)v.x; p[1] = (bf16_t)v.y; p[2] = (bf16_t)v.z; p[3] = (bf16_t)v.w;
    }
    __syncthreads();

    const int w = t >> 6, l = t & 63;
    const int lr = l & 15, lkb = (l >> 4) * 8;
    f32x4 acc[6];
#pragma unroll
    for (int i = 0; i < 6; ++i) acc[i] = (f32x4){0.f, 0.f, 0.f, 0.f};
    const bf16_t* aP = &sx[(w * 16 + lr) * LD + lkb];
    const bf16x8* wp = (const bf16x8*)wpack;
#pragma unroll
    for (int kk = 0; kk < 3; ++kk) {
        bf16x8 a = *(const bf16x8*)(aP + kk * 32);
#pragma unroll
        for (int tn = 0; tn < 6; ++tn) {
            bf16x8 b = wp[(tn * 3 + kk) * 64 + l];
            acc[tn] = __builtin_amdgcn_mfma_f32_16x16x32_bf16(a, b, acc[tn], 0, 0, 0);
        }
    }
    const int rowb = (l >> 4) * 4;
#pragma unroll
    for (int i = 0; i < 4; ++i) {
        int n = n0 + w * 16 + rowb + i;
        if (n < E) {
            int g = inv[n];
            unsigned* op = (unsigned*)(en_s + (size_t)g * 96 + lr * 6);
            op[0] = pk2(acc[0][i], acc[1][i]);
            op[1] = pk2(acc[2][i], acc[3][i]);
            op[2] = pk2(acc[4][i], acc[5][i]);
        }
    }
}

// ---------------- counting sort by dst ----------------
__global__ void hist_kernel(const int* __restrict__ dst, int* __restrict__ cnt, int E) {
    int i = blockIdx.x * 256 + threadIdx.x;
    if (i < E) atomicAdd(&cnt[dst[i]], 1);
}

__global__ __launch_bounds__(1024) void scan_kernel(const int* __restrict__ cnt,
                                                    int* __restrict__ rowptr, int N) {
    __shared__ int wsum[16];
    __shared__ int s_carry;
    const int t = threadIdx.x;
    const int w = t >> 6, l = t & 63;
    if (t == 0) s_carry = 0;
    __syncthreads();
    for (int base = 0; base < N; base += 1024) {
        int v = (base + t < N) ? cnt[base + t] : 0;
        int x = v;
#pragma unroll
        for (int d = 1; d < 64; d <<= 1) {
            int y = __shfl_up(x, d, 64);
            if (l >= d) x += y;
        }
        if (l == 63) wsum[w] = x;
        __syncthreads();
        int carry = s_carry;
        int woff = 0;
        for (int i = 0; i < w; ++i) woff += wsum[i];
        int incl = carry + woff + x;
        if (base + t < N) rowptr[base + t] = incl - v;
        __syncthreads();
        if (t == 1023) s_carry = incl;
    }
}

// writes perm (sorted->orig), inv (orig->sorted), and sorted src/dst arrays
__global__ void scatter_kernel(const int* __restrict__ dst, const int* __restrict__ src,
                               int* __restrict__ cursor,
                               int* __restrict__ perm, int* __restrict__ inv,
                               int* __restrict__ srcs, int* __restrict__ dsts, int E) {
    int i = blockIdx.x * 256 + threadIdx.x;
    if (i < E) {
        int d = dst[i];
        int p = atomicAdd(&cursor[d], 1);
        perm[p] = i;
        inv[i] = p;
        srcs[p] = src[i];
        dsts[p] = d;
    }
}

// ---------------- edge aggregation v3: no LDS tile, register run-reduction ----------------
// en_in (sorted order): Ce. out: e_new = Ce + Dh[src] + (Eh[dst]+Cb), written to
// en_out at natural slot (SCATTER_OUT=1, scatter write) or same sorted slot (0).
// sigma; BN-e stats; per-thread run reduction over its 4 sorted rows -> f32 atomics.
template <int SCATTER_OUT>
__global__ __launch_bounds__(256, 8) void edge_agg3_kernel(
    const int* __restrict__ perm, const int* __restrict__ srcs, const int* __restrict__ dsts,
    const ushort_t* __restrict__ gpack,
    const ushort_t* en_in, ushort_t* en_out,
    float* __restrict__ node_acc, float* __restrict__ stats, int E)
{
    __shared__ int ssrcS[64], sdstS[64], seidS[64];
    __shared__ float bns[96], bnq[96];
    const int t = threadIdx.x;
    const int e0 = blockIdx.x * 64;

    if (t < 64) {
        int g = e0 + t;
        bool ok = (g < E);
        sdstS[t] = ok ? dsts[g] : -1;
        ssrcS[t] = ok ? srcs[g] : 0;
        seidS[t] = (SCATTER_OUT && ok) ? perm[g] : 0;
    }
    if (t >= 64 && t < 160) { bns[t - 64] = 0.f; bnq[t - 64] = 0.f; }
    __syncthreads();

    const int w = t >> 6, l = t & 63, lr = l & 15;
    const int rowb = w * 16 + ((l >> 4) << 2);

    float ls[6] = {0, 0, 0, 0, 0, 0}, lq[6] = {0, 0, 0, 0, 0, 0};
    float ash[6], asg[6];
    int curd = -1;

#pragma unroll
    for (int i = 0; i < 4; ++i) {
        const int r = rowb + i;
        const int g = e0 + r;
        const int dd = sdstS[r];
        const bool ok = (dd >= 0);
        const int s = ssrcS[r];
        const size_t gq = ok ? (size_t)g : 0;
        const int ddu = ok ? dd : 0;
        float ce6[6], bh6[6], dh6[6], eh6[6];
        LD6(en_in + gq * 96 + lr * 6, ce6);
        LD6(gpack + (size_t)s * 288 + lr * 6, bh6);
        LD6(gpack + (size_t)s * 288 + 96 + lr * 6, dh6);
        LD6(gpack + (size_t)ddu * 288 + 192 + lr * 6, eh6);

        float sg6[6], sh6[6];
#pragma unroll
        for (int tn = 0; tn < 6; ++tn) {
            float en = ce6[tn] + dh6[tn] + eh6[tn];
            float sgv = 0.f, shv = 0.f;
            if (ok) {
                sgv = 1.f / (1.f + __expf(-en));
                shv = sgv * bh6[tn];
                ls[tn] += en; lq[tn] += en * en;
            }
            ce6[tn] = en; sg6[tn] = sgv; sh6[tn] = shv;
        }
        if (ok) {
            const size_t orow = SCATTER_OUT ? (size_t)seidS[r] : (size_t)g;
            unsigned* op = (unsigned*)(en_out + orow * 96 + lr * 6);
            op[0] = pk2(ce6[0], ce6[1]);
            op[1] = pk2(ce6[2], ce6[3]);
            op[2] = pk2(ce6[4], ce6[5]);
            if (dd != curd) {
                if (curd >= 0) {
                    float* np = node_acc + (size_t)curd * 192 + lr * 6;
#pragma unroll
                    for (int tn = 0; tn < 6; ++tn) {
                        unsafeAtomicAdd(np + tn, ash[tn]);
                        unsafeAtomicAdd(np + 96 + tn, asg[tn]);
                    }
                }
                curd = dd;
#pragma unroll
                for (int tn = 0; tn < 6; ++tn) { ash[tn] = sh6[tn]; asg[tn] = sg6[tn]; }
            } else {
#pragma unroll
                for (int tn = 0; tn < 6; ++tn) { ash[tn] += sh6[tn]; asg[tn] += sg6[tn]; }
            }
        }
    }
    if (curd >= 0) {
        float* np = node_acc + (size_t)curd * 192 + lr * 6;
#pragma unroll
        for (int tn = 0; tn < 6; ++tn) {
            unsafeAtomicAdd(np + tn, ash[tn]);
            unsafeAtomicAdd(np + 96 + tn, asg[tn]);
        }
    }

    // BN-e stats: fold lanes sharing lr
#pragma unroll
    for (int tn = 0; tn < 6; ++tn) {
        float s = ls[tn], q = lq[tn];
        s += __shfl_xor(s, 16, 64); q += __shfl_xor(q, 16, 64);
        s += __shfl_xor(s, 32, 64); q += __shfl_xor(q, 32, 64);
        if (l < 16) {
            atomicAdd(&bns[lr * 6 + tn], s);
            atomicAdd(&bnq[lr * 6 + tn], q);
        }
    }
    __syncthreads();
    if (t < 96) {
        unsafeAtomicAdd(&stats[192 + t], bns[t]);
        unsafeAtomicAdd(&stats[288 + t], bnq[t]);
    }
}

// ---------------- fallback edge aggregation (no en buffer): MFMA inside ----------------
__global__ __launch_bounds__(256) void edge_agg_fb_kernel(
    const float* __restrict__ eP, const int* __restrict__ src, const int* __restrict__ dst,
    const int* __restrict__ perm, const bf16_t* __restrict__ wpack,
    const ushort_t* __restrict__ gpack,
    float* __restrict__ node_acc, float* __restrict__ stats, int E)
{
    __shared__ int seid[64], ssrcS[64], sdstS[64];
    __shared__ float bns[96], bnq[96];

    const int t = threadIdx.x;
    const int e0 = blockIdx.x * 64;

    if (t < 64) {
        int ge = e0 + t;
        int eid = (ge < E) ? perm[ge] : -1;
        seid[t] = eid;
        ssrcS[t] = (eid >= 0) ? src[eid] : 0;
        sdstS[t] = (eid >= 0) ? dst[eid] : -1;
    }
    if (t >= 64 && t < 160) { bns[t - 64] = 0.f; bnq[t - 64] = 0.f; }
    __syncthreads();

    const int w = t >> 6, l = t & 63;
    const int lr = l & 15, lkb = (l >> 4) * 8;

    int eida = seid[w * 16 + lr];
    if (eida < 0) eida = 0;
    const float* arow = eP + (size_t)eida * 96 + lkb;
    bf16x8 a[3];
#pragma unroll
    for (int kk = 0; kk < 3; ++kk) {
        float4 a0 = *(const float4*)(arow + kk * 32);
        float4 a1 = *(const float4*)(arow + kk * 32 + 4);
        a[kk][0] = (bf16_t)a0.x; a[kk][1] = (bf16_t)a0.y;
        a[kk][2] = (bf16_t)a0.z; a[kk][3] = (bf16_t)a0.w;
        a[kk][4] = (bf16_t)a1.x; a[kk][5] = (bf16_t)a1.y;
        a[kk][6] = (bf16_t)a1.z; a[kk][7] = (bf16_t)a1.w;
    }
    f32x4 acc[6];
#pragma unroll
    for (int i = 0; i < 6; ++i) acc[i] = (f32x4){0.f, 0.f, 0.f, 0.f};
    const bf16x8* wp = (const bf16x8*)wpack;
#pragma unroll
    for (int kk = 0; kk < 3; ++kk) {
#pragma unroll
        for (int tn = 0; tn < 6; ++tn) {
            bf16x8 b = wp[(tn * 3 + kk) * 64 + l];
            acc[tn] = __builtin_amdgcn_mfma_f32_16x16x32_bf16(a[kk], b, acc[tn], 0, 0, 0);
        }
    }

    const int rowb = (l >> 4) * 4;
    float ls[6] = {0, 0, 0, 0, 0, 0}, lq[6] = {0, 0, 0, 0, 0, 0};
    float ash[6], asg[6];
    int curd = -1;
#pragma unroll
    for (int i = 0; i < 4; ++i) {
        const int r = w * 16 + rowb + i;
        const int dd = sdstS[r], s = ssrcS[r];
        const bool ok = (dd >= 0);
        const int ddu = ok ? dd : 0;
        float bh6[6], dh6[6], eh6[6];
        LD6(gpack + (size_t)s * 288 + lr * 6, bh6);
        LD6(gpack + (size_t)s * 288 + 96 + lr * 6, dh6);
        LD6(gpack + (size_t)ddu * 288 + 192 + lr * 6, eh6);
        float sh6[6], sg6[6];
#pragma unroll
        for (int tn = 0; tn < 6; ++tn) {
            float en = acc[tn][i] + dh6[tn] + eh6[tn];
            float sgv = 0.f, shv = 0.f;
            if (ok) {
                sgv = 1.f / (1.f + __expf(-en));
                shv = sgv * bh6[tn];
                ls[tn] += en; lq[tn] += en * en;
            }
            sg6[tn] = sgv; sh6[tn] = shv;
        }
        if (ok) {
            if (dd != curd) {
                if (curd >= 0) {
                    float* np = node_acc + (size_t)curd * 192 + lr * 6;
#pragma unroll
                    for (int tn = 0; tn < 6; ++tn) {
                        unsafeAtomicAdd(np + tn, ash[tn]);
                        unsafeAtomicAdd(np + 96 + tn, asg[tn]);
                    }
                }
                curd = dd;
#pragma unroll
                for (int tn = 0; tn < 6; ++tn) { ash[tn] = sh6[tn]; asg[tn] = sg6[tn]; }
            } else {
#pragma unroll
                for (int tn = 0; tn < 6; ++tn) { ash[tn] += sh6[tn]; asg[tn] += sg6[tn]; }
            }
        }
    }
    if (curd >= 0) {
        float* np = node_acc + (size_t)curd * 192 + lr * 6;
#pragma unroll
        for (int tn = 0; tn < 6; ++tn) {
            unsafeAtomicAdd(np + tn, ash[tn]);
            unsafeAtomicAdd(np + 96 + tn, asg[tn]);
        }
    }

#pragma unroll
    for (int tn = 0; tn < 6; ++tn) {
        float s = ls[tn], q = lq[tn];
        s += __shfl_xor(s, 16, 64); q += __shfl_xor(q, 16, 64);
        s += __shfl_xor(s, 32, 64); q += __shfl_xor(q, 32, 64);
        if (l < 16) {
            atomicAdd(&bns[lr * 6 + tn], s);
            atomicAdd(&bnq[lr * 6 + tn], q);
        }
    }
    __syncthreads();
    if (t < 96) {
        unsafeAtomicAdd(&stats[192 + t], bns[t]);
        unsafeAtomicAdd(&stats[288 + t], bnq[t]);
    }
}

// ---------------- streaming edge output (plan A): all-sequential ----------------
__global__ __launch_bounds__(256) void edge_out_fast_kernel(
    const float* __restrict__ eP, const ushort_t* __restrict__ en_nat,
    const float* __restrict__ coef, float* __restrict__ eout, long long total4)
{
    long long idx = (long long)blockIdx.x * 256 + threadIdx.x;
    if (idx >= total4) return;
    int c4 = (int)(idx % 24) * 4;
    float4 res = ((const float4*)eP)[idx];
    ushort4 nb = ((const ushort4*)en_nat)[idx];
    float4 o;
    o.x = res.x + fmaxf(0.f, bf2f(nb.x) * coef[192 + c4 + 0] + coef[288 + c4 + 0]);
    o.y = res.y + fmaxf(0.f, bf2f(nb.y) * coef[192 + c4 + 1] + coef[288 + c4 + 1]);
    o.z = res.z + fmaxf(0.f, bf2f(nb.z) * coef[192 + c4 + 2] + coef[288 + c4 + 2]);
    o.w = res.w + fmaxf(0.f, bf2f(nb.w) * coef[192 + c4 + 3] + coef[288 + c4 + 3]);
    ((float4*)eout)[idx] = o;
}

// ---------------- edge output (plan B): gather en from sorted slot via inv ----------------
__global__ __launch_bounds__(256) void edge_out_b_kernel(
    const float* __restrict__ eP, const ushort_t* __restrict__ en_s,
    const int* __restrict__ inv, const float* __restrict__ coef,
    float* __restrict__ eout, long long total4)
{
    long long idx = (long long)blockIdx.x * 256 + threadIdx.x;
    if (idx >= total4) return;
    int row = (int)(idx / 24);
    int c4 = (int)(idx % 24) * 4;
    float4 res = ((const float4*)eP)[idx];
    int g = inv[row];
    ushort4 nb = *(const ushort4*)(en_s + (size_t)g * 96 + c4);
    float4 o;
    o.x = res.x + fmaxf(0.f, bf2f(nb.x) * coef[192 + c4 + 0] + coef[288 + c4 + 0]);
    o.y = res.y + fmaxf(0.f, bf2f(nb.y) * coef[192 + c4 + 1] + coef[288 + c4 + 1]);
    o.z = res.z + fmaxf(0.f, bf2f(nb.z) * coef[192 + c4 + 2] + coef[288 + c4 + 2]);
    o.w = res.w + fmaxf(0.f, bf2f(nb.w) * coef[192 + c4 + 3] + coef[288 + c4 + 3]);
    ((float4*)eout)[idx] = o;
}

// ---------------- fallback edge output (recompute path, gpack gathers) ----------------
__global__ __launch_bounds__(256) void edge_out_kernel(
    const float* __restrict__ eP, const int* __restrict__ src, const int* __restrict__ dst,
    const bf16_t* __restrict__ wb, const ushort_t* __restrict__ gpack,
    const float* __restrict__ coef, float* __restrict__ eout, int E)
{
    __shared__ __align__(16) bf16_t se[64 * LD];
    __shared__ __align__(16) bf16_t sw[96 * LD];
    __shared__ int ssrc[64], sdst[64];
    const int t = threadIdx.x;
    const int e0 = blockIdx.x * 64;

    {
        const unsigned* W4 = (const unsigned*)(wb + 2 * 9216);  // C_w
        for (int i = t; i < 96 * 48; i += 256) {
            int r = i / 48, c = (i % 48) * 2;
            *(unsigned*)&sw[r * LD + c] = W4[i];
        }
    }
    for (int i = t; i < 64 * 96; i += 256) {
        int r = i / 96, c = i % 96;
        int ge = e0 + r;
        float v = (ge < E) ? eP[ge * 96 + c] : 0.f;
        se[r * LD + c] = (bf16_t)v;
    }
    if (t < 64) {
        int ge = e0 + t;
        ssrc[t] = (ge < E) ? src[ge] : 0;
        sdst[t] = (ge < E) ? dst[ge] : 0;
    }
    __syncthreads();

    const int w = t >> 6, l = t & 63;
    const int lr = l & 15, lkb = (l >> 4) * 8;
    f32x4 acc[6];
#pragma unroll
    for (int i = 0; i < 6; ++i) acc[i] = (f32x4){0.f, 0.f, 0.f, 0.f};
    const bf16_t* aP = &se[(w * 16 + lr) * LD + lkb];
#pragma unroll
    for (int kk = 0; kk < 3; ++kk) {
        bf16x8 a = *(const bf16x8*)(aP + kk * 32);
#pragma unroll
        for (int tn = 0; tn < 6; ++tn) {
            bf16x8 b = *(const bf16x8*)(&sw[(tn * 16 + lr) * LD + kk * 32 + lkb]);
            acc[tn] = __builtin_amdgcn_mfma_f32_16x16x32_bf16(a, b, acc[tn], 0, 0, 0);
        }
    }

    const int rowb = (l >> 4) * 4;
#pragma unroll
    for (int tn = 0; tn < 6; ++tn) {
        const int col = tn * 16 + lr;
        const float sc_e = coef[192 + col];
        const float sh_e = coef[288 + col];
#pragma unroll
        for (int i = 0; i < 4; ++i) {
            const int r = w * 16 + rowb + i;
            const int ge = e0 + r;
            if (ge < E) {
                const int s = ssrc[r], dd = sdst[r];
                float en = acc[tn][i] + bf2f(gpack[(size_t)s * 288 + 96 + col])
                         + bf2f(gpack[(size_t)dd * 288 + 192 + col]);
                float res = eP[ge * 96 + col];
                eout[ge * 96 + col] = res + fmaxf(0.f, en * sc_e + sh_e);
            }
        }
    }
}

// ---------------- h_new + BN-h stats ----------------
__global__ __launch_bounds__(192) void h_new_kernel(
    const float* __restrict__ nodeF_A, const float* __restrict__ node_acc,
    float* __restrict__ h_new, float* __restrict__ stats, int N)
{
    __shared__ float bs[192], bq[192];
    const int t = threadIdx.x;
    const int col = t % 96, half = t / 96;
    const int n0 = blockIdx.x * 32;
    float ls = 0.f, lq = 0.f;
    for (int r = half; r < 32; r += 2) {
        int n = n0 + r;
        if (n >= N) break;
        float ssum = node_acc[(size_t)n * 192 + 96 + col];
        float shh = node_acc[(size_t)n * 192 + col];
        float v = nodeF_A[(size_t)n * 96 + col] + shh / (ssum + 1e-6f);
        h_new[(size_t)n * 96 + col] = v;
        ls += v; lq += v * v;
    }
    bs[t] = ls; bq[t] = lq;
    __syncthreads();
    if (t < 96) {
        unsafeAtomicAdd(&stats[t], bs[t] + bs[t + 96]);
        unsafeAtomicAdd(&stats[96 + t], bq[t] + bq[t + 96]);
    }
}

// ---------------- stats -> scale/shift coefs ----------------
__global__ void finalize_stats_kernel(const float* __restrict__ stats, float* __restrict__ coef,
                                      const float* __restrict__ gh, const float* __restrict__ bh,
                                      const float* __restrict__ ge, const float* __restrict__ be,
                                      int N, int E)
{
    int t = threadIdx.x;
    if (t < 96) {
        float m = stats[t] / (float)N;
        float v = stats[96 + t] / (float)N - m * m;
        float rs = rsqrtf(v + 1e-5f);
        float sc = gh[t] * rs;
        coef[t] = sc;
        coef[96 + t] = bh[t] - m * sc;
    } else if (t < 192) {
        int c = t - 96;
        float m = stats[192 + c] / (float)E;
        float v = stats[288 + c] / (float)E - m * m;
        float rs = rsqrtf(v + 1e-5f);
        float sc = ge[c] * rs;
        coef[192 + c] = sc;
        coef[288 + c] = be[c] - m * sc;
    }
}

// ---------------- h output: h + relu(h_new*sc + sh) ----------------
__global__ __launch_bounds__(256) void h_out_kernel(
    const float* __restrict__ h, const float* __restrict__ h_new,
    const float* __restrict__ coef, float* __restrict__ out, int N)
{
    int idx = blockIdx.x * 256 + threadIdx.x;  // one float4
    int total = N * 24;
    if (idx >= total) return;
    int c4 = (idx % 24) * 4;
    float4 hv = ((const float4*)h)[idx];
    float4 nv = ((const float4*)h_new)[idx];
    float4 o;
    o.x = hv.x + fmaxf(0.f, nv.x * coef[c4 + 0] + coef[96 + c4 + 0]);
    o.y = hv.y + fmaxf(0.f, nv.y * coef[c4 + 1] + coef[96 + c4 + 1]);
    o.z = hv.z + fmaxf(0.f, nv.z * coef[c4 + 2] + coef[96 + c4 + 2]);
    o.w = hv.w + fmaxf(0.f, nv.w * coef[c4 + 3] + coef[96 + c4 + 3]);
    ((float4*)out)[idx] = o;
}

extern "C" void kernel_launch(void* const* d_in, const int* in_sizes, int n_in,
                              void* d_out, int out_size, void* d_ws, size_t ws_size,
                              hipStream_t stream)
{
    const float* h   = (const float*)d_in[0];
    const float* e   = (const float*)d_in[1];
    const int*   src = (const int*)d_in[2];
    const int*   dst = (const int*)d_in[3];
    const float* Aw  = (const float*)d_in[4];
    const float* Ab  = (const float*)d_in[5];
    const float* Bw  = (const float*)d_in[6];
    const float* Bb  = (const float*)d_in[7];
    const float* Cw  = (const float*)d_in[8];
    const float* Cb  = (const float*)d_in[9];
    const float* Dw  = (const float*)d_in[10];
    const float* Db  = (const float*)d_in[11];
    const float* Ewt = (const float*)d_in[12];
    const float* Eb  = (const float*)d_in[13];
    const float* gh  = (const float*)d_in[14];
    const float* bh  = (const float*)d_in[15];
    const float* ge  = (const float*)d_in[16];
    const float* be  = (const float*)d_in[17];

    const int N = in_sizes[0] / 96;
    const int E = in_sizes[2];

    float* ws        = (float*)d_ws;
    float* nodeF_A   = ws;                              // N*96 f32
    float* node_acc  = nodeF_A + (size_t)N * 96;        // N*192 f32
    float* hnew_reg  = node_acc + (size_t)N * 192;      // N*96 f32 (perm/srcs/dsts then h_new)
    float* stats     = hnew_reg + (size_t)N * 96;       // 384 f32
    float* coef      = stats + 384;                     // 384 f32
    bf16_t* wb       = (bf16_t*)(coef + 384);           // 5*9216 bf16
    bf16_t* wpack    = wb + 5 * 9216;                   // 1152*8 bf16 (packed C_w)
    ushort_t* gpack  = (ushort_t*)(wpack + 9216);       // N*288 bf16
    ushort_t* en_s   = gpack + (size_t)N * 288 + 16;    // E*96 bf16 (sorted Ce -> e_new)
    char* after_en   = (char*)(en_s + (size_t)E * 96);

    const size_t needB = (size_t)(after_en - (char*)d_ws) + (size_t)E * 4;        // + inv
    const size_t needA = (size_t)(after_en - (char*)d_ws) + (size_t)E * 96 * 2;   // + en_nat
    const int plan = (ws_size >= needA) ? 2 : ((ws_size >= needB) ? 1 : 0);

    // sort outputs: perm/srcs/dsts (+inv for plan A/0) live in the h_new region
    // (dead before h_new_kernel); plan B inv persists after en_s (needed by edge_out_b).
    int* perm = (int*)hnew_reg;
    int* srcs = perm + E;
    int* dsts = srcs + E;
    int* inv  = (plan == 1) ? (int*)after_en : (dsts + E);
    ushort_t* en_nat = (ushort_t*)after_en;             // plan A only

    int* cnt    = (int*)node_acc;          // N ints (before node_acc memset)
    int* rowptr = cnt + N;                 // N ints (consumed by scatter as cursor)

    hipMemsetAsync(cnt, 0, (size_t)N * sizeof(int), stream);
    conv_w_kernel<<<dim3(180), dim3(256), 0, stream>>>(Aw, Bw, Cw, Dw, Ewt, wb);
    pack_cw_kernel<<<dim3(5), dim3(256), 0, stream>>>(Cw, wpack);
    node_gemm_kernel<<<dim3((N + 63) / 64, 4), dim3(256), 0, stream>>>(
        h, wb, Ab, Bb, Db, Eb, Cb, nodeF_A, gpack, N);
    hist_kernel<<<dim3((E + 255) / 256), dim3(256), 0, stream>>>(dst, cnt, E);
    scan_kernel<<<dim3(1), dim3(1024), 0, stream>>>(cnt, rowptr, N);
    scatter_kernel<<<dim3((E + 255) / 256), dim3(256), 0, stream>>>(
        dst, src, rowptr, perm, inv, srcs, dsts, E);

    if (plan) {
        ce_gemm_kernel<<<dim3((E + 63) / 64), dim3(256), 0, stream>>>(e, wpack, inv, en_s, E);
    }

    hipMemsetAsync(node_acc, 0, (size_t)N * 192 * sizeof(float), stream);
    hipMemsetAsync(stats, 0, 384 * sizeof(float), stream);

    const int nblk = (E + 63) / 64;
    if (plan == 2) {
        edge_agg3_kernel<1><<<dim3(nblk), dim3(256), 0, stream>>>(
            perm, srcs, dsts, gpack, en_s, en_nat, node_acc, stats, E);
    } else if (plan == 1) {
        edge_agg3_kernel<0><<<dim3(nblk), dim3(256), 0, stream>>>(
            perm, srcs, dsts, gpack, en_s, en_s, node_acc, stats, E);
    } else {
        edge_agg_fb_kernel<<<dim3(nblk), dim3(256), 0, stream>>>(
            e, src, dst, perm, wpack, gpack, node_acc, stats, E);
    }

    h_new_kernel<<<dim3((N + 31) / 32), dim3(192), 0, stream>>>(
        nodeF_A, node_acc, hnew_reg, stats, N);
    finalize_stats_kernel<<<dim3(1), dim3(192), 0, stream>>>(stats, coef, gh, bh, ge, be, N, E);
    h_out_kernel<<<dim3((N * 24 + 255) / 256), dim3(256), 0, stream>>>(
        h, hnew_reg, coef, (float*)d_out, N);

    long long total4 = (long long)E * 24;
    float* eout = (float*)d_out + (size_t)N * 96;
    if (plan == 2) {
        edge_out_fast_kernel<<<dim3((unsigned)((total4 + 255) / 256)), dim3(256), 0, stream>>>(
            e, en_nat, coef, eout, total4);
    } else if (plan == 1) {
        edge_out_b_kernel<<<dim3((unsigned)((total4 + 255) / 256)), dim3(256), 0, stream>>>(
            e, en_s, inv, coef, eout, total4);
    } else {
        edge_out_kernel<<<dim3(nblk), dim3(256), 0, stream>>>(
            e, src, dst, wb, gpack, coef, eout, E);
    }
}

// Round 8
// 701.817 us; speedup vs baseline: 2.8394x; 2.8394x over previous
//
#include <hip/hip_runtime.h>
#include <hip/hip_bf16.h>

typedef __bf16 bf16_t;
typedef bf16_t bf16x8 __attribute__((ext_vector_type(8)));
typedef float f32x4 __attribute__((ext_vector_type(4)));
typedef unsigned short ushort_t;

#define LD 104   // padded LDS row stride (bf16 elems) for GEMM staging tiles

__device__ __forceinline__ float bf2f(unsigned short u) {
    return __uint_as_float(((unsigned)u) << 16);
}
__device__ __forceinline__ unsigned short f2bfu(float x) {
    union { bf16_t b; unsigned short u; } c; c.b = (bf16_t)x; return c.u;
}
__device__ __forceinline__ unsigned pk2(float x, float y) {
    return (unsigned)f2bfu(x) | ((unsigned)f2bfu(y) << 16);
}

// load 6 consecutive bf16 (as 3 dwords) -> 6 floats
#define LD6(PTR, OUT) { \
    unsigned u0 = *(const unsigned*)(PTR); \
    unsigned u1 = *(const unsigned*)((PTR) + 2); \
    unsigned u2 = *(const unsigned*)((PTR) + 4); \
    OUT[0] = bf2f(u0 & 0xffff); OUT[1] = bf2f(u0 >> 16); \
    OUT[2] = bf2f(u1 & 0xffff); OUT[3] = bf2f(u1 >> 16); \
    OUT[4] = bf2f(u2 & 0xffff); OUT[5] = bf2f(u2 >> 16); }

// ---------------- weight convert: 5 x [96][96] f32 -> bf16 ----------------
__global__ void conv_w_kernel(const float* __restrict__ A, const float* __restrict__ B,
                              const float* __restrict__ C, const float* __restrict__ Dw,
                              const float* __restrict__ Ew, bf16_t* __restrict__ wb) {
    int i = blockIdx.x * 256 + threadIdx.x;
    if (i >= 5 * 9216) return;
    int m = i / 9216, j = i % 9216;
    const float* p = (m == 0) ? A : (m == 1) ? B : (m == 2) ? C : (m == 3) ? Dw : Ew;
    wb[i] = (bf16_t)p[j];
}

// ---------------- pack C_w into per-lane MFMA B-fragment order ----------------
// col remap: tile col c (=lane&15) of tile tn -> physical col c*6 + tn
// => output column (l&15)*6 + tn lands at position (l&15)*6 + tn (natural order).
__global__ void pack_cw_kernel(const float* __restrict__ Cw, bf16_t* __restrict__ wpack) {
    int idx = blockIdx.x * 256 + threadIdx.x;
    if (idx >= 18 * 64) return;
    int frag = idx >> 6, l = idx & 63;
    int tn = frag / 3, kk = frag % 3;
    int row = (l & 15) * 6 + tn;
    int c0 = kk * 32 + (l >> 4) * 8;
    bf16_t* o = wpack + (size_t)idx * 8;
#pragma unroll
    for (int j = 0; j < 8; ++j) o[j] = (bf16_t)Cw[row * 96 + c0 + j];
}

// ---------------- node GEMM ----------------
// mat 0 -> Ah (f32, nodeF_A[n][96]); mat 1,2,3 -> Bh,Dh,El(+Cb) bf16 into gpack[n][288]
__global__ __launch_bounds__(256) void node_gemm_kernel(
    const float* __restrict__ h, const bf16_t* __restrict__ wb,
    const float* __restrict__ Ab, const float* __restrict__ Bb,
    const float* __restrict__ Db, const float* __restrict__ Eb,
    const float* __restrict__ Cb,
    float* __restrict__ nodeF_A, ushort_t* __restrict__ gpack, int N)
{
    __shared__ __align__(16) bf16_t sx[64 * LD];
    __shared__ __align__(16) bf16_t sw[96 * LD];
    const int mat = blockIdx.y;
    const int widx = (mat < 2) ? mat : mat + 1;
    const float* bias = (mat == 0) ? Ab : (mat == 1) ? Bb : (mat == 2) ? Db : Eb;
    const int n0 = blockIdx.x * 64;
    const int t = threadIdx.x;

    for (int i = t; i < 64 * 96; i += 256) {
        int r = i / 96, c = i % 96;
        int n = n0 + r;
        float v = (n < N) ? h[n * 96 + c] : 0.f;
        sx[r * LD + c] = (bf16_t)v;
    }
    {
        const unsigned* W4 = (const unsigned*)(wb + widx * 9216);
        for (int i = t; i < 96 * 48; i += 256) {
            int r = i / 48, c = (i % 48) * 2;
            *(unsigned*)&sw[r * LD + c] = W4[i];
        }
    }
    __syncthreads();

    const int w = t >> 6, l = t & 63;
    const int lr = l & 15, lkb = (l >> 4) * 8;
    f32x4 acc[6];
#pragma unroll
    for (int i = 0; i < 6; ++i) acc[i] = (f32x4){0.f, 0.f, 0.f, 0.f};
    const bf16_t* aP = &sx[(w * 16 + lr) * LD + lkb];
#pragma unroll
    for (int kk = 0; kk < 3; ++kk) {
        bf16x8 a = *(const bf16x8*)(aP + kk * 32);
#pragma unroll
        for (int tn = 0; tn < 6; ++tn) {
            bf16x8 b = *(const bf16x8*)(&sw[(tn * 16 + lr) * LD + kk * 32 + lkb]);
            acc[tn] = __builtin_amdgcn_mfma_f32_16x16x32_bf16(a, b, acc[tn], 0, 0, 0);
        }
    }
    const int rowb = (l >> 4) * 4;
#pragma unroll
    for (int tn = 0; tn < 6; ++tn) {
        const int col = tn * 16 + lr;
        float bv = bias[col];
        if (mat == 3) bv += Cb[col];
#pragma unroll
        for (int i = 0; i < 4; ++i) {
            int n = n0 + w * 16 + rowb + i;
            if (n < N) {
                float v = acc[tn][i] + bv;
                if (mat == 0) nodeF_A[(size_t)n * 96 + col] = v;
                else gpack[(size_t)n * 288 + (mat - 1) * 96 + col] = f2bfu(v);
            }
        }
    }
}

// ---------------- Ce GEMM: en_s[inv[row]][96] = bf16(e[row] @ Cw^T) ----------------
// sequential e read; scatter WRITE into dst-sorted slot (writes don't stall).
__global__ __launch_bounds__(256) void ce_gemm_kernel(
    const float* __restrict__ eP, const bf16_t* __restrict__ wpack,
    const int* __restrict__ inv, ushort_t* __restrict__ en_s, int E)
{
    __shared__ __align__(16) bf16_t sx[64 * LD];
    const int n0 = blockIdx.x * 64;
    const int t = threadIdx.x;
    for (int i = t; i < 64 * 24; i += 256) {
        int r = i / 24, c4 = i % 24;
        int n = n0 + r;
        float4 v = (n < E) ? ((const float4*)eP)[(size_t)n * 24 + c4]
                           : make_float4(0.f, 0.f, 0.f, 0.f);
        bf16_t* p = &sx[r * LD + c4 * 4];
        p[0] = (bf16_t)v.x; p[1] = (bf16_t)v.y; p[2] = (bf16_t)v.z; p[3] = (bf16_t)v.w;
    }
    __syncthreads();

    const int w = t >> 6, l = t & 63;
    const int lr = l & 15, lkb = (l >> 4) * 8;
    f32x4 acc[6];
#pragma unroll
    for (int i = 0; i < 6; ++i) acc[i] = (f32x4){0.f, 0.f, 0.f, 0.f};
    const bf16_t* aP = &sx[(w * 16 + lr) * LD + lkb];
    const bf16x8* wp = (const bf16x8*)wpack;
#pragma unroll
    for (int kk = 0; kk < 3; ++kk) {
        bf16x8 a = *(const bf16x8*)(aP + kk * 32);
#pragma unroll
        for (int tn = 0; tn < 6; ++tn) {
            bf16x8 b = wp[(tn * 3 + kk) * 64 + l];
            acc[tn] = __builtin_amdgcn_mfma_f32_16x16x32_bf16(a, b, acc[tn], 0, 0, 0);
        }
    }
    const int rowb = (l >> 4) * 4;
#pragma unroll
    for (int i = 0; i < 4; ++i) {
        int n = n0 + w * 16 + rowb + i;
        if (n < E) {
            int g = inv[n];
            unsigned* op = (unsigned*)(en_s + (size_t)g * 96 + lr * 6);
            op[0] = pk2(acc[0][i], acc[1][i]);
            op[1] = pk2(acc[2][i], acc[3][i]);
            op[2] = pk2(acc[4][i], acc[5][i]);
        }
    }
}

// ---------------- counting sort by dst ----------------
__global__ void hist_kernel(const int* __restrict__ dst, int* __restrict__ cnt, int E) {
    int i = blockIdx.x * 256 + threadIdx.x;
    if (i < E) atomicAdd(&cnt[dst[i]], 1);
}

__global__ __launch_bounds__(1024) void scan_kernel(const int* __restrict__ cnt,
                                                    int* __restrict__ rowptr, int N) {
    __shared__ int wsum[16];
    __shared__ int s_carry;
    const int t = threadIdx.x;
    const int w = t >> 6, l = t & 63;
    if (t == 0) s_carry = 0;
    __syncthreads();
    for (int base = 0; base < N; base += 1024) {
        int v = (base + t < N) ? cnt[base + t] : 0;
        int x = v;
#pragma unroll
        for (int d = 1; d < 64; d <<= 1) {
            int y = __shfl_up(x, d, 64);
            if (l >= d) x += y;
        }
        if (l == 63) wsum[w] = x;
        __syncthreads();
        int carry = s_carry;
        int woff = 0;
        for (int i = 0; i < w; ++i) woff += wsum[i];
        int incl = carry + woff + x;
        if (base + t < N) rowptr[base + t] = incl - v;
        __syncthreads();
        if (t == 1023) s_carry = incl;
    }
}

// writes perm (sorted->orig), inv (orig->sorted), sorted srcs; cursor ends = inclusive rowptr
__global__ void scatter_kernel(const int* __restrict__ dst, const int* __restrict__ src,
                               int* __restrict__ cursor,
                               int* __restrict__ perm, int* __restrict__ inv,
                               int* __restrict__ srcs, int E) {
    int i = blockIdx.x * 256 + threadIdx.x;
    if (i < E) {
        int d = dst[i];
        int p = atomicAdd(&cursor[d], 1);
        perm[p] = i;
        inv[i] = p;
        srcs[p] = src[i];
    }
}

// ---------------- CSR node-parallel aggregation (no atomics to node data) ----------------
// 16-lane group per node; lane owns cols lr*6..lr*6+5.
// en_s in: Ce (sorted). out: e_new = Ce + Dh[src] + (Eh[dst]+Cb) in place.
// Accumulates sh/sg in regs; writes h_new = Ah + sh/(sg+eps); BN-h + BN-e stats.
__global__ __launch_bounds__(256, 4) void csr_agg_kernel(
    const int* __restrict__ rowend, const int* __restrict__ srcs,
    const ushort_t* __restrict__ gpack, ushort_t* __restrict__ en_s,
    const float* __restrict__ nodeF_A, float* __restrict__ h_new,
    float* __restrict__ stats, int N)
{
    __shared__ float bns[96], bnq[96], bsh[96], bqh[96];
    const int t = threadIdx.x;
    if (t < 96) { bns[t] = 0.f; bnq[t] = 0.f; bsh[t] = 0.f; bqh[t] = 0.f; }
    __syncthreads();

    const int gi = t >> 4, lr = t & 15;
    const int n = blockIdx.x * 16 + gi;
    float ls[6] = {0, 0, 0, 0, 0, 0}, lq[6] = {0, 0, 0, 0, 0, 0};

    if (n < N) {
        const int beg = (n == 0) ? 0 : rowend[n - 1];
        const int end = rowend[n];
        float eh6[6];
        LD6(gpack + (size_t)n * 288 + 192 + lr * 6, eh6);
        float ash[6] = {0, 0, 0, 0, 0, 0}, asg[6] = {0, 0, 0, 0, 0, 0};

        int sNext = (beg < end) ? srcs[beg] : 0;
        for (int g = beg; g < end; ++g) {
            const int s = sNext;
            if (g + 1 < end) sNext = srcs[g + 1];
            float ce6[6], bh6[6], dh6[6];
            LD6(en_s + (size_t)g * 96 + lr * 6, ce6);
            LD6(gpack + (size_t)s * 288 + lr * 6, bh6);
            LD6(gpack + (size_t)s * 288 + 96 + lr * 6, dh6);
            float en6[6];
#pragma unroll
            for (int k = 0; k < 6; ++k) {
                float en = ce6[k] + dh6[k] + eh6[k];
                float sg = 1.f / (1.f + __expf(-en));
                ash[k] += sg * bh6[k];
                asg[k] += sg;
                ls[k] += en; lq[k] += en * en;
                en6[k] = en;
            }
            unsigned* op = (unsigned*)(en_s + (size_t)g * 96 + lr * 6);
            op[0] = pk2(en6[0], en6[1]);
            op[1] = pk2(en6[2], en6[3]);
            op[2] = pk2(en6[4], en6[5]);
        }

        const float* ap = nodeF_A + (size_t)n * 96 + lr * 6;
        float* hp = h_new + (size_t)n * 96 + lr * 6;
#pragma unroll
        for (int k = 0; k < 6; ++k) {
            float v = ap[k] + ash[k] / (asg[k] + 1e-6f);
            hp[k] = v;
            atomicAdd(&bsh[lr * 6 + k], v);
            atomicAdd(&bqh[lr * 6 + k], v * v);
        }
    }
#pragma unroll
    for (int k = 0; k < 6; ++k) {
        atomicAdd(&bns[lr * 6 + k], ls[k]);
        atomicAdd(&bnq[lr * 6 + k], lq[k]);
    }
    __syncthreads();
    if (t < 96) {
        unsafeAtomicAdd(&stats[t], bsh[t]);
        unsafeAtomicAdd(&stats[96 + t], bqh[t]);
        unsafeAtomicAdd(&stats[192 + t], bns[t]);
        unsafeAtomicAdd(&stats[288 + t], bnq[t]);
    }
}

// ---------------- edge output: natural order, gather e_new via inv ----------------
__global__ __launch_bounds__(256) void edge_out_b_kernel(
    const float* __restrict__ eP, const ushort_t* __restrict__ en_s,
    const int* __restrict__ inv, const float* __restrict__ coef,
    float* __restrict__ eout, long long total4)
{
    long long idx = (long long)blockIdx.x * 256 + threadIdx.x;
    if (idx >= total4) return;
    int row = (int)(idx / 24);
    int c4 = (int)(idx % 24) * 4;
    float4 res = ((const float4*)eP)[idx];
    int g = inv[row];
    ushort4 nb = *(const ushort4*)(en_s + (size_t)g * 96 + c4);
    float4 o;
    o.x = res.x + fmaxf(0.f, bf2f(nb.x) * coef[192 + c4 + 0] + coef[288 + c4 + 0]);
    o.y = res.y + fmaxf(0.f, bf2f(nb.y) * coef[192 + c4 + 1] + coef[288 + c4 + 1]);
    o.z = res.z + fmaxf(0.f, bf2f(nb.z) * coef[192 + c4 + 2] + coef[288 + c4 + 2]);
    o.w = res.w + fmaxf(0.f, bf2f(nb.w) * coef[192 + c4 + 3] + coef[288 + c4 + 3]);
    ((float4*)eout)[idx] = o;
}

// ---------------- fallback edge aggregation (atomic path, small ws) ----------------
__global__ __launch_bounds__(256) void edge_agg_fb_kernel(
    const float* __restrict__ eP, const int* __restrict__ src, const int* __restrict__ dst,
    const int* __restrict__ perm, const bf16_t* __restrict__ wpack,
    const ushort_t* __restrict__ gpack,
    float* __restrict__ node_acc, float* __restrict__ stats, int E)
{
    __shared__ int seid[64], ssrcS[64], sdstS[64];
    __shared__ float bns[96], bnq[96];

    const int t = threadIdx.x;
    const int e0 = blockIdx.x * 64;

    if (t < 64) {
        int ge = e0 + t;
        int eid = (ge < E) ? perm[ge] : -1;
        seid[t] = eid;
        ssrcS[t] = (eid >= 0) ? src[eid] : 0;
        sdstS[t] = (eid >= 0) ? dst[eid] : -1;
    }
    if (t >= 64 && t < 160) { bns[t - 64] = 0.f; bnq[t - 64] = 0.f; }
    __syncthreads();

    const int w = t >> 6, l = t & 63;
    const int lr = l & 15, lkb = (l >> 4) * 8;

    int eida = seid[w * 16 + lr];
    if (eida < 0) eida = 0;
    const float* arow = eP + (size_t)eida * 96 + lkb;
    bf16x8 a[3];
#pragma unroll
    for (int kk = 0; kk < 3; ++kk) {
        float4 a0 = *(const float4*)(arow + kk * 32);
        float4 a1 = *(const float4*)(arow + kk * 32 + 4);
        a[kk][0] = (bf16_t)a0.x; a[kk][1] = (bf16_t)a0.y;
        a[kk][2] = (bf16_t)a0.z; a[kk][3] = (bf16_t)a0.w;
        a[kk][4] = (bf16_t)a1.x; a[kk][5] = (bf16_t)a1.y;
        a[kk][6] = (bf16_t)a1.z; a[kk][7] = (bf16_t)a1.w;
    }
    f32x4 acc[6];
#pragma unroll
    for (int i = 0; i < 6; ++i) acc[i] = (f32x4){0.f, 0.f, 0.f, 0.f};
    const bf16x8* wp = (const bf16x8*)wpack;
#pragma unroll
    for (int kk = 0; kk < 3; ++kk) {
#pragma unroll
        for (int tn = 0; tn < 6; ++tn) {
            bf16x8 b = wp[(tn * 3 + kk) * 64 + l];
            acc[tn] = __builtin_amdgcn_mfma_f32_16x16x32_bf16(a[kk], b, acc[tn], 0, 0, 0);
        }
    }

    const int rowb = (l >> 4) * 4;
    float ls[6] = {0, 0, 0, 0, 0, 0}, lq[6] = {0, 0, 0, 0, 0, 0};
#pragma unroll
    for (int i = 0; i < 4; ++i) {
        const int r = w * 16 + rowb + i;
        const int dd = sdstS[r], s = ssrcS[r];
        const bool ok = (dd >= 0);
        const int ddu = ok ? dd : 0;
        float bh6[6], dh6[6], eh6[6];
        LD6(gpack + (size_t)s * 288 + lr * 6, bh6);
        LD6(gpack + (size_t)s * 288 + 96 + lr * 6, dh6);
        LD6(gpack + (size_t)ddu * 288 + 192 + lr * 6, eh6);
#pragma unroll
        for (int tn = 0; tn < 6; ++tn) {
            float en = acc[tn][i] + dh6[tn] + eh6[tn];
            if (ok) {
                float sgv = 1.f / (1.f + __expf(-en));
                float shv = sgv * bh6[tn];
                ls[tn] += en; lq[tn] += en * en;
                unsafeAtomicAdd(node_acc + (size_t)dd * 192 + lr * 6 + tn, shv);
                unsafeAtomicAdd(node_acc + (size_t)dd * 192 + 96 + lr * 6 + tn, sgv);
            }
        }
    }

#pragma unroll
    for (int tn = 0; tn < 6; ++tn) {
        float s = ls[tn], q = lq[tn];
        s += __shfl_xor(s, 16, 64); q += __shfl_xor(q, 16, 64);
        s += __shfl_xor(s, 32, 64); q += __shfl_xor(q, 32, 64);
        if (l < 16) {
            atomicAdd(&bns[lr * 6 + tn], s);
            atomicAdd(&bnq[lr * 6 + tn], q);
        }
    }
    __syncthreads();
    if (t < 96) {
        unsafeAtomicAdd(&stats[192 + t], bns[t]);
        unsafeAtomicAdd(&stats[288 + t], bnq[t]);
    }
}

// ---------------- fallback h_new + BN-h stats ----------------
__global__ __launch_bounds__(192) void h_new_kernel(
    const float* __restrict__ nodeF_A, const float* __restrict__ node_acc,
    float* __restrict__ h_new, float* __restrict__ stats, int N)
{
    __shared__ float bs[192], bq[192];
    const int t = threadIdx.x;
    const int col = t % 96, half = t / 96;
    const int n0 = blockIdx.x * 32;
    float ls = 0.f, lq = 0.f;
    for (int r = half; r < 32; r += 2) {
        int n = n0 + r;
        if (n >= N) break;
        float ssum = node_acc[(size_t)n * 192 + 96 + col];
        float shh = node_acc[(size_t)n * 192 + col];
        float v = nodeF_A[(size_t)n * 96 + col] + shh / (ssum + 1e-6f);
        h_new[(size_t)n * 96 + col] = v;
        ls += v; lq += v * v;
    }
    bs[t] = ls; bq[t] = lq;
    __syncthreads();
    if (t < 96) {
        unsafeAtomicAdd(&stats[t], bs[t] + bs[t + 96]);
        unsafeAtomicAdd(&stats[96 + t], bq[t] + bq[t + 96]);
    }
}

// ---------------- fallback edge output (recompute path, gpack gathers) ----------------
__global__ __launch_bounds__(256) void edge_out_kernel(
    const float* __restrict__ eP, const int* __restrict__ src, const int* __restrict__ dst,
    const bf16_t* __restrict__ wpack, const ushort_t* __restrict__ gpack,
    const float* __restrict__ coef, float* __restrict__ eout, int E)
{
    const int t = threadIdx.x;
    const int e0 = blockIdx.x * 64;
    const int w = t >> 6, l = t & 63;
    const int lr = l & 15, lkb = (l >> 4) * 8;

    int eida = e0 + w * 16 + (l & 15);
    if (eida >= E) eida = E - 1;
    const float* arow = eP + (size_t)eida * 96 + lkb;
    bf16x8 a[3];
#pragma unroll
    for (int kk = 0; kk < 3; ++kk) {
        float4 a0 = *(const float4*)(arow + kk * 32);
        float4 a1 = *(const float4*)(arow + kk * 32 + 4);
        a[kk][0] = (bf16_t)a0.x; a[kk][1] = (bf16_t)a0.y;
        a[kk][2] = (bf16_t)a0.z; a[kk][3] = (bf16_t)a0.w;
        a[kk][4] = (bf16_t)a1.x; a[kk][5] = (bf16_t)a1.y;
        a[kk][6] = (bf16_t)a1.z; a[kk][7] = (bf16_t)a1.w;
    }
    f32x4 acc[6];
#pragma unroll
    for (int i = 0; i < 6; ++i) acc[i] = (f32x4){0.f, 0.f, 0.f, 0.f};
    const bf16x8* wp = (const bf16x8*)wpack;
#pragma unroll
    for (int kk = 0; kk < 3; ++kk) {
#pragma unroll
        for (int tn = 0; tn < 6; ++tn) {
            bf16x8 b = wp[(tn * 3 + kk) * 64 + l];
            acc[tn] = __builtin_amdgcn_mfma_f32_16x16x32_bf16(a[kk], b, acc[tn], 0, 0, 0);
        }
    }

    const int rowb = (l >> 4) * 4;
#pragma unroll
    for (int i = 0; i < 4; ++i) {
        const int r = w * 16 + rowb + i;
        const int ge = e0 + r;
        if (ge < E) {
            const int s = src[ge], dd = dst[ge];
            float dh6[6], eh6[6];
            LD6(gpack + (size_t)s * 288 + 96 + lr * 6, dh6);
            LD6(gpack + (size_t)dd * 288 + 192 + lr * 6, eh6);
#pragma unroll
            for (int tn = 0; tn < 6; ++tn) {
                const int col = lr * 6 + tn;
                float en = acc[tn][i] + dh6[tn] + eh6[tn];
                float res = eP[(size_t)ge * 96 + col];
                eout[(size_t)ge * 96 + col] =
                    res + fmaxf(0.f, en * coef[192 + col] + coef[288 + col]);
            }
        }
    }
}

// ---------------- stats -> scale/shift coefs ----------------
__global__ void finalize_stats_kernel(const float* __restrict__ stats, float* __restrict__ coef,
                                      const float* __restrict__ gh, const float* __restrict__ bh,
                                      const float* __restrict__ ge, const float* __restrict__ be,
                                      int N, int E)
{
    int t = threadIdx.x;
    if (t < 96) {
        float m = stats[t] / (float)N;
        float v = stats[96 + t] / (float)N - m * m;
        float rs = rsqrtf(v + 1e-5f);
        float sc = gh[t] * rs;
        coef[t] = sc;
        coef[96 + t] = bh[t] - m * sc;
    } else if (t < 192) {
        int c = t - 96;
        float m = stats[192 + c] / (float)E;
        float v = stats[288 + c] / (float)E - m * m;
        float rs = rsqrtf(v + 1e-5f);
        float sc = ge[c] * rs;
        coef[192 + c] = sc;
        coef[288 + c] = be[c] - m * sc;
    }
}

// ---------------- h output: h + relu(h_new*sc + sh) ----------------
__global__ __launch_bounds__(256) void h_out_kernel(
    const float* __restrict__ h, const float* __restrict__ h_new,
    const float* __restrict__ coef, float* __restrict__ out, int N)
{
    int idx = blockIdx.x * 256 + threadIdx.x;  // one float4
    int total = N * 24;
    if (idx >= total) return;
    int c4 = (idx % 24) * 4;
    float4 hv = ((const float4*)h)[idx];
    float4 nv = ((const float4*)h_new)[idx];
    float4 o;
    o.x = hv.x + fmaxf(0.f, nv.x * coef[c4 + 0] + coef[96 + c4 + 0]);
    o.y = hv.y + fmaxf(0.f, nv.y * coef[c4 + 1] + coef[96 + c4 + 1]);
    o.z = hv.z + fmaxf(0.f, nv.z * coef[c4 + 2] + coef[96 + c4 + 2]);
    o.w = hv.w + fmaxf(0.f, nv.w * coef[c4 + 3] + coef[96 + c4 + 3]);
    ((float4*)out)[idx] = o;
}

extern "C" void kernel_launch(void* const* d_in, const int* in_sizes, int n_in,
                              void* d_out, int out_size, void* d_ws, size_t ws_size,
                              hipStream_t stream)
{
    const float* h   = (const float*)d_in[0];
    const float* e   = (const float*)d_in[1];
    const int*   src = (const int*)d_in[2];
    const int*   dst = (const int*)d_in[3];
    const float* Aw  = (const float*)d_in[4];
    const float* Ab  = (const float*)d_in[5];
    const float* Bw  = (const float*)d_in[6];
    const float* Bb  = (const float*)d_in[7];
    const float* Cw  = (const float*)d_in[8];
    const float* Cb  = (const float*)d_in[9];
    const float* Dw  = (const float*)d_in[10];
    const float* Db  = (const float*)d_in[11];
    const float* Ewt = (const float*)d_in[12];
    const float* Eb  = (const float*)d_in[13];
    const float* gh  = (const float*)d_in[14];
    const float* bh  = (const float*)d_in[15];
    const float* ge  = (const float*)d_in[16];
    const float* be  = (const float*)d_in[17];

    const int N = in_sizes[0] / 96;
    const int E = in_sizes[2];

    float* ws        = (float*)d_ws;
    float* nodeF_A   = ws;                              // N*96 f32
    float* regR      = nodeF_A + (size_t)N * 96;        // N*192 f32 (idx arrays / fb node_acc)
    float* h_new     = regR + (size_t)N * 192;          // N*96 f32
    float* stats     = h_new + (size_t)N * 96;          // 384 f32
    float* coef      = stats + 384;                     // 384 f32
    bf16_t* wb       = (bf16_t*)(coef + 384);           // 5*9216 bf16
    bf16_t* wpack    = wb + 5 * 9216;                   // 1152*8 bf16 (packed C_w)
    ushort_t* gpack  = (ushort_t*)(wpack + 9216);       // N*288 bf16
    ushort_t* en_s   = gpack + (size_t)N * 288 + 16;    // E*96 bf16 (sorted Ce -> e_new)

    const size_t need_main = (size_t)((char*)(en_s + (size_t)E * 96) - (char*)d_ws);
    const bool main_ok = (ws_size >= need_main) &&
                         ((size_t)(2 * N + 4 * E) * 4 <= (size_t)N * 192 * 4);
    const int nblk64 = (E + 63) / 64;

    if (main_ok) {
        // idx arrays live in regR (node_acc not needed on this path)
        int* cnt    = (int*)regR;
        int* rowptr = cnt + N;        // after scatter: inclusive row ends
        int* perm   = rowptr + N;
        int* srcs   = perm + E;
        int* dsts_u = srcs + E;       // unused slot (kept for layout clarity)
        int* inv    = dsts_u + E;
        (void)dsts_u;

        hipMemsetAsync(cnt, 0, (size_t)N * sizeof(int), stream);
        hipMemsetAsync(stats, 0, 384 * sizeof(float), stream);
        conv_w_kernel<<<dim3(180), dim3(256), 0, stream>>>(Aw, Bw, Cw, Dw, Ewt, wb);
        pack_cw_kernel<<<dim3(5), dim3(256), 0, stream>>>(Cw, wpack);
        node_gemm_kernel<<<dim3((N + 63) / 64, 4), dim3(256), 0, stream>>>(
            h, wb, Ab, Bb, Db, Eb, Cb, nodeF_A, gpack, N);
        hist_kernel<<<dim3((E + 255) / 256), dim3(256), 0, stream>>>(dst, cnt, E);
        scan_kernel<<<dim3(1), dim3(1024), 0, stream>>>(cnt, rowptr, N);
        scatter_kernel<<<dim3((E + 255) / 256), dim3(256), 0, stream>>>(
            dst, src, rowptr, perm, inv, srcs, E);
        ce_gemm_kernel<<<dim3(nblk64), dim3(256), 0, stream>>>(e, wpack, inv, en_s, E);

        csr_agg_kernel<<<dim3((N + 15) / 16), dim3(256), 0, stream>>>(
            rowptr, srcs, gpack, en_s, nodeF_A, h_new, stats, N);

        finalize_stats_kernel<<<dim3(1), dim3(192), 0, stream>>>(stats, coef, gh, bh, ge, be, N, E);
        h_out_kernel<<<dim3((N * 24 + 255) / 256), dim3(256), 0, stream>>>(
            h, h_new, coef, (float*)d_out, N);

        long long total4 = (long long)E * 24;
        edge_out_b_kernel<<<dim3((unsigned)((total4 + 255) / 256)), dim3(256), 0, stream>>>(
            e, en_s, inv, coef, (float*)d_out + (size_t)N * 96, total4);
    } else {
        // fallback: atomic aggregation, recompute edge output (no en_s buffer)
        float* node_acc = regR;
        int* perm = (int*)h_new;      // dead before h_new_kernel? no — fb h_new_kernel
                                      // writes h_new AFTER agg consumed perm. OK.
        int* inv  = perm + E;         // unused by fb kernels
        int* srcs = inv + E;          // unused by fb kernels
        int* cnt    = (int*)node_acc;
        int* rowptr = cnt + N;

        hipMemsetAsync(cnt, 0, (size_t)N * sizeof(int), stream);
        conv_w_kernel<<<dim3(180), dim3(256), 0, stream>>>(Aw, Bw, Cw, Dw, Ewt, wb);
        pack_cw_kernel<<<dim3(5), dim3(256), 0, stream>>>(Cw, wpack);
        node_gemm_kernel<<<dim3((N + 63) / 64, 4), dim3(256), 0, stream>>>(
            h, wb, Ab, Bb, Db, Eb, Cb, nodeF_A, gpack, N);
        hist_kernel<<<dim3((E + 255) / 256), dim3(256), 0, stream>>>(dst, cnt, E);
        scan_kernel<<<dim3(1), dim3(1024), 0, stream>>>(cnt, rowptr, N);
        scatter_kernel<<<dim3((E + 255) / 256), dim3(256), 0, stream>>>(
            dst, src, rowptr, perm, inv, srcs, E);

        hipMemsetAsync(node_acc, 0, (size_t)N * 192 * sizeof(float), stream);
        hipMemsetAsync(stats, 0, 384 * sizeof(float), stream);

        edge_agg_fb_kernel<<<dim3(nblk64), dim3(256), 0, stream>>>(
            e, src, dst, perm, wpack, gpack, node_acc, stats, E);
        h_new_kernel<<<dim3((N + 31) / 32), dim3(192), 0, stream>>>(
            nodeF_A, node_acc, h_new, stats, N);
        finalize_stats_kernel<<<dim3(1), dim3(192), 0, stream>>>(stats, coef, gh, bh, ge, be, N, E);
        h_out_kernel<<<dim3((N * 24 + 255) / 256), dim3(256), 0, stream>>>(
            h, h_new, coef, (float*)d_out, N);
        edge_out_kernel<<<dim3(nblk64), dim3(256), 0, stream>>>(
            e, src, dst, wpack, gpack, coef, (float*)d_out + (size_t)N * 96, E);
    }
}